// Round 1
// baseline (25.313 us; speedup 1.0000x reference)
//
#include <hip/hip_runtime.h>

#define VOCABSZ 50000
#define EMB 128
#define RADIUS 3
#define REGION 7
#define BB 16
#define LL 2048

// One 32-lane group per (b,l) output row; each lane holds float4 (4 of 128 dims).
// 8 rows per 256-thread block -> grid = B*L/8 = 4096 blocks.
__global__ __launch_bounds__(256) void trigram_emb_kernel(
    const int* __restrict__ seq,   // [B*L] int32
    const float* __restrict__ W,   // [VOCAB*REGION, EMB] f32
    float* __restrict__ out)       // [B*L, EMB] f32
{
    const int row  = blockIdx.x * 8 + (threadIdx.x >> 5);  // b*L + l
    const int lane = threadIdx.x & 31;
    const int l    = row & (LL - 1);
    const int base = row - l;                              // b*L

    float4 acc = make_float4(0.f, 0.f, 0.f, 0.f);
#pragma unroll
    for (int i = 0; i < REGION; ++i) {
        int pos = l - RADIUS + i;
        int tok = (pos >= 0 && pos < LL) ? seq[base + pos] : 0;
        const float4* wrow =
            reinterpret_cast<const float4*>(W + (size_t)(tok * REGION + i) * EMB);
        float4 v = wrow[lane];
        acc.x += v.x; acc.y += v.y; acc.z += v.z; acc.w += v.w;
    }

    const float mask = (seq[row] != 0) ? 1.0f : 0.0f;
    float4 r;
    r.x = tanhf(acc.x) * mask;
    r.y = tanhf(acc.y) * mask;
    r.z = tanhf(acc.z) * mask;
    r.w = tanhf(acc.w) * mask;
    reinterpret_cast<float4*>(out)[(size_t)row * 32 + lane] = r;
}

extern "C" void kernel_launch(void* const* d_in, const int* in_sizes, int n_in,
                              void* d_out, int out_size, void* d_ws, size_t ws_size,
                              hipStream_t stream) {
    const int*   seq = (const int*)d_in[0];    // [B, L, 1] int32
    const float* W   = (const float*)d_in[1];  // [VOCAB*REGION, EMB] f32
    float*       out = (float*)d_out;          // [B, L, 1, EMB] f32

    const int rows = BB * LL;                  // 32768
    dim3 grid(rows / 8), block(256);
    hipLaunchKernelGGL(trigram_emb_kernel, grid, block, 0, stream, seq, W, out);
}